// Round 9
// baseline (99.227 us; speedup 1.0000x reference)
//
#include <hip/hip_runtime.h>

#define N_IN 512
#define N_VP 12
#define BATCH 65536

#define WAVES 4                   // waves per block; wave s owns a col quarter
#define ROWS 64                   // rows per block (= lanes per wave)
#define CPW (N_IN / WAVES)        // 128 cols per wave
#define CHUNK 16                  // cols per staged chunk (R5-verified layout)
#define NCHW (CPW / CHUNK)        // 8 chunks per wave

// ---------------------------------------------------------------------------
// Single fused kernel.
//   Phase 0: issue chunk-0 x loads (stream starts at t~0; W-build hides under
//            the saturated memory pipe -- model M: per-CU read ceiling).
//   Phase 1: per-block W = phi * Ginv in LDS (fp32 Newton, math identical to
//            the R5-verified build_W kernel; phiT [12][512] built in wlds,
//            then in-place re-laid to W [512][12] via a register transpose).
//   Phase 2: R5 pipeline: coalesced loads + XOR q-swizzle (HW-verified),
//            single LDS buf per wave (in-order DS, R8-verified), prefetch-1,
//            W via uniform-address ds_read_b128 broadcasts.
//   Phase 3: cross-wave reduce in LDS, float4 out.
// ---------------------------------------------------------------------------
__global__ __launch_bounds__(256, 4) void vp_fused_kernel(const float* __restrict__ x,
                                                          const float* __restrict__ w,
                                                          float* __restrict__ out) {
    __shared__ float wlds[N_IN * N_VP];             // 24 KB: phiT -> W
    __shared__ float stage[WAVES * ROWS * CHUNK];   // 16 KB: staging / build scratch / reduce

    const int tid  = threadIdx.x;
    const int lane = tid & 63;
    const int s    = __builtin_amdgcn_readfirstlane(tid >> 6);
    const int qx   = (lane >> 1) & 3;
    const size_t rowbase = (size_t)blockIdx.x * ROWS;
    const float* __restrict__ xq = x + rowbase * N_IN + s * CPW;

    // per-lane swizzled global offsets (R5-hardware-verified mapping):
    // staging instr i, lane: tile float4 f=i*64+lane -> row t=f>>2, slot q0=f&3,
    // global col-group qg = q0 ^ ((t>>1)&3)  (permutation within each 64B line)
    int off[4];
#pragma unroll
    for (int i = 0; i < 4; ++i) {
        const int f = i * 64 + lane, t = f >> 2, q0 = f & 3;
        const int qg = q0 ^ ((t >> 1) & 3);
        off[i] = t * N_IN + qg * 4;
    }

    // ---- Phase 0: chunk-0 loads in flight before any barrier ----
    float4 pre[4];
#pragma unroll
    for (int i = 0; i < 4; ++i)
        pre[i] = *reinterpret_cast<const float4*>(xq + off[i]);

    // ---- Phase 1: W build (replicated per block; identical fp32 math) ----
    const float dil = w[0];
    const float tr  = w[1];

#pragma unroll
    for (int half = 0; half < 2; ++half) {           // phiT[k][n], n=tid, tid+256
        const int n = tid + half * 256;
        const float t  = (float)n - 0.5f * (float)(N_IN - 1);
        const float xs = dil * (t - tr);
        float pm2 = 0.7511255444649425f * expf(-0.5f * xs * xs);   // pi^-1/4
        float pm1 = 1.4142135623730951f * xs * pm2;
        wlds[0 * N_IN + n] = pm2;
        wlds[1 * N_IN + n] = pm1;
#pragma unroll
        for (int k = 2; k < N_VP; ++k) {
            const float pk = sqrtf(2.0f / (float)k) * xs * pm1
                           - sqrtf((float)(k - 1) / (float)k) * pm2;
            wlds[k * N_IN + n] = pk;
            pm2 = pm1; pm1 = pk;
        }
    }
    __syncthreads();

    float* const Gp = stage;           // [2][78] partial dots
    float* const G  = stage + 160;     // [12][12]
    float* const Y  = stage + 304;     // [12][12]
    float* const T  = stage + 448;     // [12][12]

    if (tid < 156) {                   // G upper triangle: 78 pairs x 2 halves
        const int p = tid >> 1, h = tid & 1;
        int i = 0, rem = p;
        while (rem >= N_VP - i) { rem -= N_VP - i; ++i; }
        const int j = i + rem;
        const float4* __restrict__ pi =
            reinterpret_cast<const float4*>(wlds + i * N_IN + h * 256);
        const float4* __restrict__ pj =
            reinterpret_cast<const float4*>(wlds + j * N_IN + h * 256);
        float acc = 0.0f;
#pragma unroll 4
        for (int q = 0; q < 64; ++q) {
            const float4 a = pi[q], b = pj[q];
            acc += a.x * b.x + a.y * b.y + a.z * b.z + a.w * b.w;
        }
        Gp[h * 78 + p] = acc;
    }
    __syncthreads();
    if (tid < 78) {
        int i = 0, rem = tid;
        while (rem >= N_VP - i) { rem -= N_VP - i; ++i; }
        const int j = i + rem;
        const float v = Gp[tid] + Gp[78 + tid];
        G[i * N_VP + j] = v;
        G[j * N_VP + i] = v;
    }
    if (tid < 144) {
        const int ii = tid / N_VP, jj = tid % N_VP;
        Y[tid] = (ii == jj) ? dil : 0.0f;             // Y0 = dil * I
    }
    __syncthreads();

    for (int it = 0; it < 3; ++it) {                  // Newton: Y <- Y(2I - G Y)
        if (tid < 144) {
            const int ii = tid / N_VP, jj = tid % N_VP;
            float sa = 0.0f;
#pragma unroll
            for (int k = 0; k < N_VP; ++k) sa += G[ii * N_VP + k] * Y[k * N_VP + jj];
            T[tid] = sa;
        }
        __syncthreads();
        float v = 0.0f;
        if (tid < 144) {
            const int ii = tid / N_VP, jj = tid % N_VP;
            float sa = 0.0f;
#pragma unroll
            for (int k = 0; k < N_VP; ++k) sa += Y[ii * N_VP + k] * T[k * N_VP + jj];
            v = 2.0f * Y[tid] - sa;
        }
        __syncthreads();
        if (tid < 144) Y[tid] = v;
        __syncthreads();
    }

    // W rows (n=tid, tid+256) into regs, then in-place layout change to [n][k]
    float w0[N_VP], w1[N_VP];
#pragma unroll
    for (int k = 0; k < N_VP; ++k) {
        float s0 = 0.0f, s1 = 0.0f;
#pragma unroll
        for (int j = 0; j < N_VP; ++j) {
            const float yk = Y[k * N_VP + j];
            s0 += yk * wlds[j * N_IN + tid];
            s1 += yk * wlds[j * N_IN + tid + 256];
        }
        w0[k] = s0; w1[k] = s1;
    }
    __syncthreads();                                  // all phiT reads complete
#pragma unroll
    for (int k = 0; k < N_VP; ++k) {
        wlds[tid * N_VP + k]         = w0[k];
        wlds[(tid + 256) * N_VP + k] = w1[k];
    }
    __syncthreads();                                  // W ready; stage free

    // ---- Phase 2: main pipeline (R5 structure, single buf, prefetch-1) ----
    float4* const sb4 = reinterpret_cast<float4*>(stage + s * (ROWS * CHUNK));

    float acc[N_VP];
#pragma unroll
    for (int k = 0; k < N_VP; ++k) acc[k] = 0.0f;

#pragma unroll
    for (int c = 0; c < NCHW; ++c) {
        // chunk c (regs) -> wave-private LDS slice
#pragma unroll
        for (int i = 0; i < 4; ++i) sb4[i * 64 + lane] = pre[i];
        // prefetch chunk c+1 (in flight during compute(c))
        if (c + 1 < NCHW) {
#pragma unroll
            for (int i = 0; i < 4; ++i)
                pre[i] = *reinterpret_cast<const float4*>(xq + off[i] + (c + 1) * CHUNK);
        }
        // compute chunk c; W via uniform-address ds_read_b128 (broadcast)
        const float* __restrict__ wc = wlds + (s * CPW + c * CHUNK) * N_VP;
#pragma unroll
        for (int q = 0; q < 4; ++q) {
            const float4 xv = sb4[(lane << 2) + (q ^ qx)];
            const float* __restrict__ w4 = wc + q * (4 * N_VP);
#pragma unroll
            for (int k = 0; k < N_VP; ++k) acc[k] = fmaf(xv.x, w4[k], acc[k]);
#pragma unroll
            for (int k = 0; k < N_VP; ++k) acc[k] = fmaf(xv.y, w4[N_VP + k], acc[k]);
#pragma unroll
            for (int k = 0; k < N_VP; ++k) acc[k] = fmaf(xv.z, w4[2 * N_VP + k], acc[k]);
#pragma unroll
            for (int k = 0; k < N_VP; ++k) acc[k] = fmaf(xv.w, w4[3 * N_VP + k], acc[k]);
        }
    }

    // ---- Phase 3: cross-wave reduce over the 4 col-quarters ----
    __syncthreads();
    float4* part4 = reinterpret_cast<float4*>(stage);   // [4][64*3] float4 = 12 KB
    part4[s * 192 + lane * 3 + 0] = make_float4(acc[0], acc[1], acc[2],  acc[3]);
    part4[s * 192 + lane * 3 + 1] = make_float4(acc[4], acc[5], acc[6],  acc[7]);
    part4[s * 192 + lane * 3 + 2] = make_float4(acc[8], acc[9], acc[10], acc[11]);
    __syncthreads();
    if (tid < 192) {
        const float4 v0 = part4[tid],       v1 = part4[192 + tid];
        const float4 v2 = part4[384 + tid], v3 = part4[576 + tid];
        float4 r;
        r.x = (v0.x + v1.x) + (v2.x + v3.x);
        r.y = (v0.y + v1.y) + (v2.y + v3.y);
        r.z = (v0.z + v1.z) + (v2.z + v3.z);
        r.w = (v0.w + v1.w) + (v2.w + v3.w);
        reinterpret_cast<float4*>(out + rowbase * N_VP)[tid] = r;
    }
}

extern "C" void kernel_launch(void* const* d_in, const int* in_sizes, int n_in,
                              void* d_out, int out_size, void* d_ws, size_t ws_size,
                              hipStream_t stream) {
    const float* x  = (const float*)d_in[0];   // [65536, 512] fp32
    const float* w  = (const float*)d_in[1];   // [2] fp32
    float* out      = (float*)d_out;           // [65536, 12] fp32

    vp_fused_kernel<<<BATCH / ROWS, 256, 0, stream>>>(x, w, out);
}

// Round 10
// 68.680 us; speedup vs baseline: 1.4448x; 1.4448x over previous
//
#include <hip/hip_runtime.h>

#define N_IN 512
#define N_VP 12
#define BATCH 65536

#define ROWS 64                    // rows per block
#define NSTRIP 4                   // strips per row-tile
#define SCOLS 128                  // cols per strip
#define SF4 (ROWS * SCOLS / 4)     // 2048 float4 per strip (32 KB)

// ---------------------------------------------------------------------------
// Kernel A (1 block, 512 threads, fp32): W = phi * Ginv  [512][12]
//   Ginv via Newton Y <- Y(2I - G Y), Y0 = dil*I.  (R8-verified, absmax 0.0039)
// ---------------------------------------------------------------------------
__global__ __launch_bounds__(512) void build_W_kernel(const float* __restrict__ w,
                                                      float* __restrict__ Wg) {
    __shared__ float sphiT[N_VP][N_IN];        // transposed: rows contiguous (24 KB)
    __shared__ float Gp[2][N_VP][N_VP];
    __shared__ float G[N_VP][N_VP], Y[N_VP][N_VP], T[N_VP][N_VP];

    const int tid = threadIdx.x;
    const float dil = w[0];
    const float tr  = w[1];

    float ph[N_VP];
    {
        const float t  = (float)tid - 0.5f * (float)(N_IN - 1);
        const float xs = dil * (t - tr);
        ph[0] = 0.7511255444649425f * expf(-0.5f * xs * xs);   // pi^-1/4
        ph[1] = 1.4142135623730951f * xs * ph[0];
#pragma unroll
        for (int k = 2; k < N_VP; ++k)
            ph[k] = sqrtf(2.0f / (float)k) * xs * ph[k - 1]
                  - sqrtf((float)(k - 1) / (float)k) * ph[k - 2];
#pragma unroll
        for (int k = 0; k < N_VP; ++k) sphiT[k][tid] = ph[k];
    }
    __syncthreads();

    if (tid < 288) {                 // G = phi^T phi : 2 threads per (i,j)
        const int p = tid >> 1;
        const int i = p / N_VP, j = p % N_VP;
        const int m0 = (tid & 1) * 256;
        const float4* __restrict__ pi = reinterpret_cast<const float4*>(&sphiT[i][m0]);
        const float4* __restrict__ pj = reinterpret_cast<const float4*>(&sphiT[j][m0]);
        float s = 0.0f;
#pragma unroll 4
        for (int q = 0; q < 64; ++q) {
            const float4 a = pi[q], b = pj[q];
            s += a.x * b.x + a.y * b.y + a.z * b.z + a.w * b.w;
        }
        Gp[tid & 1][i][j] = s;
    }
    __syncthreads();
    const int ii = (tid < 144) ? tid / N_VP : 0;
    const int jj = (tid < 144) ? tid % N_VP : 0;
    if (tid < 144) {
        G[ii][jj] = Gp[0][ii][jj] + Gp[1][ii][jj];
        Y[ii][jj] = (ii == jj) ? dil : 0.0f;
    }
    __syncthreads();

    for (int it = 0; it < 3; ++it) {
        if (tid < 144) {
            float s = 0.0f;
#pragma unroll
            for (int k = 0; k < N_VP; ++k) s += G[ii][k] * Y[k][jj];
            T[ii][jj] = s;
        }
        __syncthreads();
        float v = 0.0f;
        if (tid < 144) {
            float s = 0.0f;
#pragma unroll
            for (int k = 0; k < N_VP; ++k) s += Y[ii][k] * T[k][jj];
            v = 2.0f * Y[ii][jj] - s;
        }
        __syncthreads();
        if (tid < 144) Y[ii][jj] = v;
        __syncthreads();
    }

#pragma unroll
    for (int k = 0; k < N_VP; ++k) {          // W[n][k] = sum_j Y[k][j] phi[n][j]
        float s = 0.0f;
#pragma unroll
        for (int j2 = 0; j2 < N_VP; ++j2) s += Y[k][j2] * ph[j2];
        Wg[tid * N_VP + k] = s;
    }
}

// ---------------------------------------------------------------------------
// Kernel B: out = x @ W.  SEQUENTIAL-SEGMENT round.
//   Block = 256 thr = 4 waves, tile = 64 rows.  Per strip s (64 rows x 128
//   cols = 32 KB), ALL threads cooperatively stage it with 512B-sequential
//   runs (32 lanes cover one row's strip segment).  Compute: thread t owns
//   row t&63, col window (t>>6)*32 within each strip -> W index wave-uniform
//   (SGPR s_loads, R5-verified).  XOR slot swizzle (cg ^ (row&7)) on write
//   and read -> b128 bank floor on both sides.  Prefetch distance 1 (8 f4
//   regs), 2 barriers per strip.  Cross-window reduce in LDS at the end.
// ---------------------------------------------------------------------------
__global__ __launch_bounds__(256) void coeffs_kernel(const float* __restrict__ x,
                                                     const float* __restrict__ Wg,
                                                     float* __restrict__ out) {
    __shared__ float4 sb[SF4];                 // 32 KB strip buffer (swizzled)
    const int tid  = threadIdx.x;
    const int lane = tid & 63;
    const int g    = __builtin_amdgcn_readfirstlane(tid >> 6);  // col window
    const size_t rowbase = (size_t)blockIdx.x * ROWS;
    const float* __restrict__ xbase = x + rowbase * N_IN;

    // staging map: instr i (0..7): row r = i*8 + (tid>>5), colgrp cg = tid&31
    //   -> 32 consecutive lanes read 512B of one row (sequential run).
    const int r_st = tid >> 5;                 // 0..7
    const int cg   = tid & 31;

    float4 pre[8];
#define LOADS(s)                                                               \
    { _Pragma("unroll")                                                        \
      for (int i_ = 0; i_ < 8; ++i_)                                           \
        pre[i_] = *reinterpret_cast<const float4*>(                            \
            xbase + (size_t)(i_ * 8 + r_st) * N_IN + (s) * SCOLS + cg * 4); }
#define STORES()                                                               \
    { _Pragma("unroll")                                                        \
      for (int i_ = 0; i_ < 8; ++i_) {                                         \
        const int r_ = i_ * 8 + r_st;                                          \
        sb[r_ * 32 + (cg ^ (r_ & 7))] = pre[i_]; } }

    LOADS(0)
    STORES()
    LOADS(1)

    float acc[N_VP];
#pragma unroll
    for (int k = 0; k < N_VP; ++k) acc[k] = 0.0f;

    __syncthreads();                           // strip 0 visible

#pragma unroll
    for (int s = 0; s < NSTRIP; ++s) {
        // compute strip s: thread = row `lane`, col window g (32 cols)
        const float* __restrict__ wb = Wg + (s * SCOLS + g * 32) * N_VP;
#pragma unroll
        for (int j = 0; j < 8; ++j) {
            const float4 xv = sb[lane * 32 + ((g * 8 + j) ^ (lane & 7))];
            const float* __restrict__ w4 = wb + j * (4 * N_VP);
#pragma unroll
            for (int k = 0; k < N_VP; ++k) acc[k] = fmaf(xv.x, w4[k], acc[k]);
#pragma unroll
            for (int k = 0; k < N_VP; ++k) acc[k] = fmaf(xv.y, w4[N_VP + k], acc[k]);
#pragma unroll
            for (int k = 0; k < N_VP; ++k) acc[k] = fmaf(xv.z, w4[2 * N_VP + k], acc[k]);
#pragma unroll
            for (int k = 0; k < N_VP; ++k) acc[k] = fmaf(xv.w, w4[3 * N_VP + k], acc[k]);
        }
        if (s < NSTRIP - 1) {
            __syncthreads();                   // all reads of strip s done
            STORES()                           // strip s+1 -> LDS
            if (s < NSTRIP - 2) LOADS(s + 2)   // strip s+2 in flight
            __syncthreads();                   // strip s+1 visible
        }
    }

    // ---- cross-window reduce over the 4 col windows (reuses sb; guarded) ----
    __syncthreads();
    float4* part4 = sb;                        // [4][64*3] float4 = 12 KB
    part4[g * 192 + lane * 3 + 0] = make_float4(acc[0], acc[1], acc[2],  acc[3]);
    part4[g * 192 + lane * 3 + 1] = make_float4(acc[4], acc[5], acc[6],  acc[7]);
    part4[g * 192 + lane * 3 + 2] = make_float4(acc[8], acc[9], acc[10], acc[11]);
    __syncthreads();
    if (tid < 192) {
        const float4 v0 = part4[tid],       v1 = part4[192 + tid];
        const float4 v2 = part4[384 + tid], v3 = part4[576 + tid];
        float4 r;
        r.x = (v0.x + v1.x) + (v2.x + v3.x);
        r.y = (v0.y + v1.y) + (v2.y + v3.y);
        r.z = (v0.z + v1.z) + (v2.z + v3.z);
        r.w = (v0.w + v1.w) + (v2.w + v3.w);
        reinterpret_cast<float4*>(out + rowbase * N_VP)[tid] = r;
    }
}

extern "C" void kernel_launch(void* const* d_in, const int* in_sizes, int n_in,
                              void* d_out, int out_size, void* d_ws, size_t ws_size,
                              hipStream_t stream) {
    const float* x  = (const float*)d_in[0];   // [65536, 512] fp32
    const float* w  = (const float*)d_in[1];   // [2] fp32
    float* out      = (float*)d_out;           // [65536, 12] fp32
    float* Wg       = (float*)d_ws;            // [512][12] fp32

    build_W_kernel<<<1, 512, 0, stream>>>(w, Wg);
    coeffs_kernel<<<BATCH / ROWS, 256, 0, stream>>>(x, Wg, out);
}

// Round 11
// 42.927 us; speedup vs baseline: 2.3115x; 1.5999x over previous
//
#include <hip/hip_runtime.h>

#define N_IN 512
#define N_VP 12
#define BATCH 65536

#define SPLIT 4                   // col quarters; wave s of each block owns one
#define ROWS 64                   // rows per block (= lanes per wave)
#define CPW (N_IN / SPLIT)        // 128 cols per wave
#define CHUNK 16                  // cols staged per chunk
#define NCHW (CPW / CHUNK)        // 8 chunks per wave

// ---------------------------------------------------------------------------
// Kernel A (1 block, 512 threads, fp32): W = phi * Ginv  [512][12]
//   Ginv via Newton Y <- Y(2I - G Y), Y0 = dil*I (G ~ (1/dil) I).
//   R5-verified: absmax 0.0039.
// ---------------------------------------------------------------------------
__global__ __launch_bounds__(512) void build_W_kernel(const float* __restrict__ w,
                                                      float* __restrict__ Wg) {
    __shared__ float sphiT[N_VP][N_IN];        // transposed: rows contiguous (24 KB)
    __shared__ float Gp[2][N_VP][N_VP];
    __shared__ float G[N_VP][N_VP], Y[N_VP][N_VP], T[N_VP][N_VP];

    const int tid = threadIdx.x;
    const float dil = w[0];
    const float tr  = w[1];

    float ph[N_VP];
    {
        const float t  = (float)tid - 0.5f * (float)(N_IN - 1);
        const float xs = dil * (t - tr);
        ph[0] = 0.7511255444649425f * expf(-0.5f * xs * xs);   // pi^-1/4
        ph[1] = 1.4142135623730951f * xs * ph[0];
#pragma unroll
        for (int k = 2; k < N_VP; ++k)
            ph[k] = sqrtf(2.0f / (float)k) * xs * ph[k - 1]
                  - sqrtf((float)(k - 1) / (float)k) * ph[k - 2];
#pragma unroll
        for (int k = 0; k < N_VP; ++k) sphiT[k][tid] = ph[k];
    }
    __syncthreads();

    if (tid < 288) {                 // G = phi^T phi : 2 threads per (i,j)
        const int p = tid >> 1;
        const int i = p / N_VP, j = p % N_VP;
        const int m0 = (tid & 1) * 256;
        const float4* __restrict__ pi = reinterpret_cast<const float4*>(&sphiT[i][m0]);
        const float4* __restrict__ pj = reinterpret_cast<const float4*>(&sphiT[j][m0]);
        float s = 0.0f;
#pragma unroll 4
        for (int q = 0; q < 64; ++q) {
            const float4 a = pi[q], b = pj[q];
            s += a.x * b.x + a.y * b.y + a.z * b.z + a.w * b.w;
        }
        Gp[tid & 1][i][j] = s;
    }
    __syncthreads();
    const int ii = (tid < 144) ? tid / N_VP : 0;
    const int jj = (tid < 144) ? tid % N_VP : 0;
    if (tid < 144) {
        G[ii][jj] = Gp[0][ii][jj] + Gp[1][ii][jj];
        Y[ii][jj] = (ii == jj) ? dil : 0.0f;
    }
    __syncthreads();

    for (int it = 0; it < 3; ++it) {
        if (tid < 144) {
            float s = 0.0f;
#pragma unroll
            for (int k = 0; k < N_VP; ++k) s += G[ii][k] * Y[k][jj];
            T[ii][jj] = s;
        }
        __syncthreads();
        float v = 0.0f;
        if (tid < 144) {
            float s = 0.0f;
#pragma unroll
            for (int k = 0; k < N_VP; ++k) s += Y[ii][k] * T[k][jj];
            v = 2.0f * Y[ii][jj] - s;
        }
        __syncthreads();
        if (tid < 144) Y[ii][jj] = v;
        __syncthreads();
    }

#pragma unroll
    for (int k = 0; k < N_VP; ++k) {          // W[n][k] = sum_j Y[k][j] phi[n][j]
        float s = 0.0f;
#pragma unroll
        for (int j2 = 0; j2 < N_VP; ++j2) s += Y[k][j2] * ph[j2];
        Wg[tid * N_VP + k] = s;
    }
}

// ---------------------------------------------------------------------------
// Kernel B: out = x @ W, fused split-K + reduce.  (R5-verified: best measured,
//   42.8 us total; effective read ~3.6 TB/s = measured chip read ceiling.)
//   Block = 256 thr = 4 waves; wave s owns cols [s*128,(s+1)*128) of 64 rows.
//   Coalesced global -> regs -> LDS (XOR q-swizzle; reads at 8-access/bank
//   floor), wave-private double buffer => no barriers in the pipeline.
//   W via wave-uniform SGPR loads. Final cross-wave reduce in LDS (2 barriers).
//
//   Buffer roles per iteration c:
//     cur = (c&1)?preB:preA  -- held chunk c, already staged to LDS -> free;
//                               receives the chunk c+2 global load.
//     nxt = (c&1)?preA:preB  -- holds chunk c+1 in regs; gets stored to LDS.
// ---------------------------------------------------------------------------
__device__ __forceinline__ void load_chunk(const float* __restrict__ xq,
                                           const int off[4], int c, float4 pre[4]) {
#pragma unroll
    for (int i = 0; i < 4; ++i)
        pre[i] = *reinterpret_cast<const float4*>(xq + off[i] + c * CHUNK);
}

__device__ __forceinline__ void store_chunk(float4* __restrict__ dst, int lane,
                                            const float4 pre[4]) {
#pragma unroll
    for (int i = 0; i < 4; ++i) dst[i * 64 + lane] = pre[i];
}

__device__ __forceinline__ void compute_chunk(const float4* __restrict__ buf,
                                              int lane, int qx,
                                              const float* __restrict__ wb,
                                              float acc[N_VP]) {
#pragma unroll
    for (int q = 0; q < 4; ++q) {
        const float4 xv = buf[(lane << 2) + (q ^ qx)];   // global col-group q
        const float* __restrict__ w4 = wb + q * (4 * N_VP);
#pragma unroll
        for (int k = 0; k < N_VP; ++k) acc[k] = fmaf(xv.x, w4[k], acc[k]);
#pragma unroll
        for (int k = 0; k < N_VP; ++k) acc[k] = fmaf(xv.y, w4[N_VP + k], acc[k]);
#pragma unroll
        for (int k = 0; k < N_VP; ++k) acc[k] = fmaf(xv.z, w4[2 * N_VP + k], acc[k]);
#pragma unroll
        for (int k = 0; k < N_VP; ++k) acc[k] = fmaf(xv.w, w4[3 * N_VP + k], acc[k]);
    }
}

__global__ __launch_bounds__(256, 4) void coeffs_kernel(const float* __restrict__ x,
                                                        const float* __restrict__ Wg,
                                                        float* __restrict__ out) {
    __shared__ float4 sb[SPLIT][2][256];       // 32 KB; wave-private slices
    const int tid  = threadIdx.x;
    const int lane = tid & 63;
    const int s    = __builtin_amdgcn_readfirstlane(tid >> 6);
    const int qx   = (lane >> 1) & 3;
    const size_t rowbase = (size_t)blockIdx.x * ROWS;
    const float* __restrict__ xq = x + rowbase * N_IN + (size_t)s * CPW;
    const float* __restrict__ wbase = Wg + s * CPW * N_VP;

    // lane-dependent global float4 offsets (floats), constant across chunks.
    // staging instr i, lane: tile float4 f = i*64+lane -> row t=f>>2, slot q0=f&3,
    // global col-group qg = q0 ^ ((t>>1)&3)  (XOR swizzle, stays within 64B line)
    int off[4];
#pragma unroll
    for (int i = 0; i < 4; ++i) {
        const int f = i * 64 + lane, t = f >> 2, q0 = f & 3;
        const int qg = q0 ^ ((t >> 1) & 3);
        off[i] = t * N_IN + qg * 4;
    }

    float4 preA[4], preB[4];
    load_chunk(xq, off, 0, preA);
    load_chunk(xq, off, 1, preB);
    store_chunk(&sb[s][0][0], lane, preA);

    float acc[N_VP];
#pragma unroll
    for (int k = 0; k < N_VP; ++k) acc[k] = 0.0f;

#pragma unroll
    for (int c = 0; c < NCHW; ++c) {
        // nxt (holds chunk c+1) -> LDS; then chunk c+2 -> cur (freed buffer).
        if (c + 1 < NCHW) store_chunk(&sb[s][(c + 1) & 1][0], lane,
                                      (c & 1) ? preA : preB);   // nxt
        if (c + 2 < NCHW) load_chunk(xq, off, c + 2,
                                     (c & 1) ? preB : preA);    // cur
        compute_chunk(&sb[s][c & 1][0], lane, qx, wbase + c * (CHUNK * N_VP), acc);
    }

    // ---- cross-wave reduce over s (aliases staging area; barrier-guarded) ----
    __syncthreads();
    float4* part4 = reinterpret_cast<float4*>(&sb[0][0][0]);   // [4][64][3] float4
    part4[s * 192 + lane * 3 + 0] = make_float4(acc[0], acc[1], acc[2],  acc[3]);
    part4[s * 192 + lane * 3 + 1] = make_float4(acc[4], acc[5], acc[6],  acc[7]);
    part4[s * 192 + lane * 3 + 2] = make_float4(acc[8], acc[9], acc[10], acc[11]);
    __syncthreads();
    if (tid < 192) {
        const float4 v0 = part4[tid], v1 = part4[192 + tid];
        const float4 v2 = part4[384 + tid], v3 = part4[576 + tid];
        float4 r;
        r.x = (v0.x + v1.x) + (v2.x + v3.x);
        r.y = (v0.y + v1.y) + (v2.y + v3.y);
        r.z = (v0.z + v1.z) + (v2.z + v3.z);
        r.w = (v0.w + v1.w) + (v2.w + v3.w);
        reinterpret_cast<float4*>(out + rowbase * N_VP)[tid] = r;
    }
}

extern "C" void kernel_launch(void* const* d_in, const int* in_sizes, int n_in,
                              void* d_out, int out_size, void* d_ws, size_t ws_size,
                              hipStream_t stream) {
    const float* x  = (const float*)d_in[0];   // [65536, 512] fp32
    const float* w  = (const float*)d_in[1];   // [2] fp32
    float* out      = (float*)d_out;           // [65536, 12] fp32
    float* Wg       = (float*)d_ws;            // [512][12] fp32

    build_W_kernel<<<1, 512, 0, stream>>>(w, Wg);
    coeffs_kernel<<<BATCH / ROWS, 256, 0, stream>>>(x, Wg, out);
}